// Round 8
// baseline (588.813 us; speedup 1.0000x reference)
//
#include <hip/hip_runtime.h>

// MultiFeatureRNNModel: 2-layer tanh RNN (H1=5,H2=3), B=8192, T=512, F=16,
// final-step FC(3->1)+sigmoid.
//
// Two-phase split (each phase independently roofline-predictable):
//   phase 1: xp[t][b][5] = x[b][t,:] @ W_ih1^T + (b_ih1+b_hh1)   (to d_ws)
//            streaming, 2048 waves, coalesced writes. floor ~53 us.
//   phase 2: per-seq serial scan over t (both layers in-register),
//            xp reads coalesced (lane=b), 8-step double-buffered prefetch.
//            issue/latency-bound ~40-60 us; xp is L3-resident.

namespace {
constexpr int kB  = 8192;
constexpr int kT  = 512;
constexpr int kF  = 16;
constexpr int kH1 = 5;
constexpr int kH2 = 3;

constexpr int TC = 32;                 // timesteps per phase-1 thread
constexpr int CH = 8;                  // phase-2 chunk (double-buffered)

// float4 with 4-byte alignment (xp rows are 20B-strided, not 16B-aligned)
typedef float v4 __attribute__((ext_vector_type(4), aligned(4)));

__device__ __forceinline__ float fast_tanh(float v) {
    // tanh(v) = 1 - 2/(exp(2v)+1); saturates correctly at +-1.
    float e = __expf(v + v);
    return 1.0f - __fdividef(2.0f, e + 1.0f);
}
}  // namespace

// ---------------- phase 1: input projection ----------------
__global__ __launch_bounds__(256) void rnn_p1_xproj(
    const float* __restrict__ x,      // [B,T,F]
    const float* __restrict__ W_ih1,  // [H1,F]
    const float* __restrict__ b_ih1,  // [H1]
    const float* __restrict__ b_hh1,  // [H1]
    float* __restrict__ xp)           // [T,B,5]
{
    const int gid = blockIdx.x * 256 + threadIdx.x;   // 0..131071
    const int b   = gid & (kB - 1);                   // lane-consecutive b
    const int tc  = gid >> 13;                        // 0..15

    float w1[kH1][kF], bs[kH1];
#pragma unroll
    for (int h = 0; h < kH1; ++h) {
        bs[h] = b_ih1[h] + b_hh1[h];
#pragma unroll
        for (int f = 0; f < kF; ++f) w1[h][f] = W_ih1[h * kF + f];
    }

    const float4* xb = reinterpret_cast<const float4*>(x) +
                       ((size_t)b * kT + (size_t)tc * TC) * 4;

#pragma unroll 4
    for (int j = 0; j < TC; ++j) {
        const float4 q0 = xb[j * 4 + 0];
        const float4 q1 = xb[j * 4 + 1];
        const float4 q2 = xb[j * 4 + 2];
        const float4 q3 = xb[j * 4 + 3];
        const float xv[kF] = {q0.x, q0.y, q0.z, q0.w, q1.x, q1.y, q1.z, q1.w,
                              q2.x, q2.y, q2.z, q2.w, q3.x, q3.y, q3.z, q3.w};
        float a[kH1];
#pragma unroll
        for (int h = 0; h < kH1; ++h) {
            float acc = bs[h];
#pragma unroll
            for (int f = 0; f < kF; ++f) acc = fmaf(xv[f], w1[h][f], acc);
            a[h] = acc;
        }
        const int t = tc * TC + j;
        float* p = xp + ((size_t)t * kB + b) * 5;
        v4 q; q[0] = a[0]; q[1] = a[1]; q[2] = a[2]; q[3] = a[3];
        *reinterpret_cast<v4*>(p) = q;     // dwordx4 @ 4B align
        p[4] = a[4];
    }
}

// ---------------- phase 2: serial scan ----------------
__global__ __launch_bounds__(64) void rnn_p2_scan(
    const float* __restrict__ xp,     // [T,B,5]
    const float* __restrict__ W_hh1,  // [H1,H1]
    const float* __restrict__ W_ih2,  // [H2,H1]
    const float* __restrict__ W_hh2,  // [H2,H2]
    const float* __restrict__ b_ih2,  // [H2]
    const float* __restrict__ b_hh2,  // [H2]
    const float* __restrict__ W_fc,   // [1,H2]
    const float* __restrict__ b_fc,   // [1]
    float* __restrict__ out)          // [B]
{
    const int b = blockIdx.x * 64 + threadIdx.x;

    float whh1[kH1][kH1];
#pragma unroll
    for (int h = 0; h < kH1; ++h)
#pragma unroll
        for (int j = 0; j < kH1; ++j) whh1[h][j] = W_hh1[h * kH1 + j];

    float wih2[kH2][kH1], whh2[kH2][kH2], bs2[kH2], wfc[kH2];
#pragma unroll
    for (int m = 0; m < kH2; ++m) {
        bs2[m] = b_ih2[m] + b_hh2[m];
        wfc[m] = W_fc[m];
#pragma unroll
        for (int j = 0; j < kH1; ++j) wih2[m][j] = W_ih2[m * kH1 + j];
#pragma unroll
        for (int j = 0; j < kH2; ++j) whh2[m][j] = W_hh2[m * kH2 + j];
    }
    const float bfc = b_fc[0];

    float h1[kH1] = {0.f, 0.f, 0.f, 0.f, 0.f};
    float h2[kH2] = {0.f, 0.f, 0.f};

    // per-lane base: xp + b*5 floats; per-t stride = kB*5 floats
    const char* basep = reinterpret_cast<const char*>(xp + (size_t)b * 5);
    constexpr size_t TSTRIDE = (size_t)kB * 5 * sizeof(float);

    v4 A4[CH]; float A1[CH];
    v4 B4[CH]; float B1[CH];

    auto LOADC = [&](v4* Q4, float* Q1, int c) {
#pragma unroll
        for (int i = 0; i < CH; ++i) {
            const float* p = reinterpret_cast<const float*>(
                basep + (size_t)(c * CH + i) * TSTRIDE);
            Q4[i] = *reinterpret_cast<const v4*>(p);
            Q1[i] = p[4];
        }
    };

    auto STEP8 = [&](const v4* Q4, const float* Q1) {
#pragma unroll
        for (int i = 0; i < CH; ++i) {
            float a[kH1];
#pragma unroll
            for (int h = 0; h < kH1; ++h) {
                float acc = (h < 4) ? Q4[i][h] : Q1[i];
#pragma unroll
                for (int j = 0; j < kH1; ++j)
                    acc = fmaf(h1[j], whh1[h][j], acc);
                a[h] = acc;
            }
#pragma unroll
            for (int h = 0; h < kH1; ++h) h1[h] = fast_tanh(a[h]);

            float c2[kH2];
#pragma unroll
            for (int m = 0; m < kH2; ++m) {
                float acc = bs2[m];
#pragma unroll
                for (int j = 0; j < kH1; ++j)
                    acc = fmaf(h1[j], wih2[m][j], acc);
#pragma unroll
                for (int j = 0; j < kH2; ++j)
                    acc = fmaf(h2[j], whh2[m][j], acc);
                c2[m] = acc;
            }
#pragma unroll
            for (int m = 0; m < kH2; ++m) h2[m] = fast_tanh(c2[m]);
        }
    };

    LOADC(A4, A1, 0);
    constexpr int NCH = kT / CH;   // 64
    for (int c = 0; c < NCH; c += 2) {
        LOADC(B4, B1, c + 1);
        STEP8(A4, A1);
        if (c + 2 < NCH) LOADC(A4, A1, c + 2);
        STEP8(B4, B1);
    }

    float z = bfc;
#pragma unroll
    for (int m = 0; m < kH2; ++m) z = fmaf(h2[m], wfc[m], z);
    out[b] = __fdividef(1.0f, 1.0f + __expf(-z));
}

extern "C" void kernel_launch(void* const* d_in, const int* in_sizes, int n_in,
                              void* d_out, int out_size, void* d_ws, size_t ws_size,
                              hipStream_t stream) {
    const float* x     = (const float*)d_in[0];
    const float* W_ih1 = (const float*)d_in[1];
    const float* W_hh1 = (const float*)d_in[2];
    const float* b_ih1 = (const float*)d_in[3];
    const float* b_hh1 = (const float*)d_in[4];
    const float* W_ih2 = (const float*)d_in[5];
    const float* W_hh2 = (const float*)d_in[6];
    const float* b_ih2 = (const float*)d_in[7];
    const float* b_hh2 = (const float*)d_in[8];
    const float* W_fc  = (const float*)d_in[9];
    const float* b_fc  = (const float*)d_in[10];
    float* out = (float*)d_out;
    float* xp  = (float*)d_ws;   // 512*8192*5*4 = 80 MiB

    // phase 1: 131072 threads = 512 blocks x 256
    rnn_p1_xproj<<<dim3(512), dim3(256), 0, stream>>>(x, W_ih1, b_ih1, b_hh1, xp);
    // phase 2: 8192 threads = 128 blocks x 64
    rnn_p2_scan<<<dim3(128), dim3(64), 0, stream>>>(
        xp, W_hh1, W_ih2, W_hh2, b_ih2, b_hh2, W_fc, b_fc, out);
}